// Round 14
// baseline (70.048 us; speedup 1.0000x reference)
//
#include <hip/hip_runtime.h>

#define NROW 8192
#define MDIM 128
#define KLAB 16
#define NSLAB 64                     // 8192 / 128 supertile rows
#define NTILE (NSLAB*(NSLAB+1)/2)    // 2080 upper-tri supertiles
#define MARGINP2 288.0f              // (1.5*sqrt(128))^2: clamp bound, min folded into clamp

typedef __attribute__((ext_vector_type(8))) short  s16x8;
typedef __attribute__((ext_vector_type(4))) float  f32x4;

#if __has_builtin(__builtin_amdgcn_sqrtf)
#define FSQRT(x) __builtin_amdgcn_sqrtf(x)
#else
#define FSQRT(x) sqrtf(x)
#endif
#if __has_builtin(__builtin_amdgcn_rcpf)
#define FRCP(x) __builtin_amdgcn_rcpf(x)
#else
#define FRCP(x) (1.0f / (x))
#endif
#if __has_builtin(__builtin_amdgcn_fmed3f)
#define FCLAMP(x) __builtin_amdgcn_fmed3f((x), 0.0f, MARGINP2)
#else
#define FCLAMP(x) fminf(fmaxf((x), 0.0f), MARGINP2)
#endif

__device__ __forceinline__ unsigned short f2bf(float x) {
  unsigned u = __float_as_uint(x);            // RTNE bf16, inputs finite
  return (unsigned short)((u + 0x7FFFu + ((u >> 16) & 1u)) >> 16);
}

// Wave handles 4 rows: bf16 convert + sumsq + npos + fp8 label bytes (1.0 -> 0x38).
__global__ void prep_kernel(const float* __restrict__ feat, const int* __restrict__ label,
                            unsigned short* __restrict__ fbf, float2* __restrict__ sqnp,
                            unsigned char* __restrict__ posf8) {
  int wv = threadIdx.x >> 6, lane = threadIdx.x & 63;
  int sub = lane >> 4, l16 = lane & 15;
  int row = blockIdx.x * 16 + wv * 4 + sub;
  const float* rp = feat + (size_t)row * MDIM + l16 * 8;
  float4 va = *reinterpret_cast<const float4*>(rp);
  float4 vb = *reinterpret_cast<const float4*>(rp + 4);
  s16x8 st;
  st[0]=(short)f2bf(va.x); st[1]=(short)f2bf(va.y); st[2]=(short)f2bf(va.z); st[3]=(short)f2bf(va.w);
  st[4]=(short)f2bf(vb.x); st[5]=(short)f2bf(vb.y); st[6]=(short)f2bf(vb.z); st[7]=(short)f2bf(vb.w);
  *reinterpret_cast<s16x8*>(fbf + (size_t)row * MDIM + l16 * 8) = st;
  float s = va.x*va.x + va.y*va.y + va.z*va.z + va.w*va.w
          + vb.x*vb.x + vb.y*vb.y + vb.z*vb.z + vb.w*vb.w;
  #pragma unroll
  for (int off = 8; off >= 1; off >>= 1) s += __shfl_xor(s, off);   // reduce within 16-lane row group
  int lab = label[((size_t)blockIdx.x * 16 + wv * 4) * KLAB + lane];
  bool on = lab > 0;
  unsigned long long bal = __ballot(on);
  posf8[(size_t)row * KLAB + l16] = on ? 0x38 : 0x00;               // fp8 e4m3 1.0 / 0.0
  if (l16 == 0) {
    unsigned m = (unsigned)((bal >> (sub * 16)) & 0xFFFFull);
    sqnp[row] = make_float2(s, (float)__popc(m));
  }
}

// Block = 8 waves (4x2 grid) = one 128x128 supertile (bi<=bj).
// B slab (32 KB) in LDS XOR-swizzled; A fragments direct from L2-resident global (once).
// inter/union via fp8 MFMA (pos . pos^T on the idle matrix pipe) - R13 ablation showed
// the popc/cvt chain was ~half the epilogue cost. mfma bf16 layout verified R2 (absmax 0).
__global__ __launch_bounds__(512, 2) void pair_main(
    const unsigned short* __restrict__ fbf, const float2* __restrict__ sqnp,
    const unsigned char* __restrict__ posf8, float* __restrict__ part) {
  __shared__ char smem[32768];            // B slab
  __shared__ float bsum[8];

  int bi = 0, rem = blockIdx.x;
  while (rem >= NSLAB - bi) { rem -= NSLAB - bi; bi++; }
  int bj = bi + rem;
  bool diag = (bi == bj);

  int wv = threadIdx.x >> 6, lane = threadIdx.x & 63;
  int l15 = lane & 15, lg = lane >> 4;
  int wr = wv >> 1, wc = wv & 1;          // 4x2 wave grid: 32 rows x 64 cols each
  const char* fb = (const char*)fbf;
  int arow = bi * 128 + wr * 32;

  // ---- A fragments + A labels direct from global (issued before B staging) ----
  s16x8 af[2][4];
  #pragma unroll
  for (int fi = 0; fi < 2; fi++)
    #pragma unroll
    for (int ks = 0; ks < 4; ks++)
      af[fi][ks] = *reinterpret_cast<const s16x8*>(
          fb + (size_t)(arow + fi * 16 + l15) * 256 + ks * 64 + lg * 16);
  long long alab[2];
  #pragma unroll
  for (int fi = 0; fi < 2; fi++) {
    int row = arow + fi * 16 + l15;                   // fragment row = l15
    alab[fi] = (lg < 2) ? *reinterpret_cast<const long long*>(posf8 + (size_t)row * KLAB + lg * 8)
                        : 0LL;                        // k=16..31 zero pad
  }

  // ---- metadata: {sq, npos} packed float2 loads ----
  float sqi[2][4], nif[2][4];
  #pragma unroll
  for (int fi = 0; fi < 2; fi++)
    #pragma unroll
    for (int r = 0; r < 4; r++) {
      float2 v = sqnp[arow + fi * 16 + lg * 4 + r];   // C/D row = lg*4 + r
      sqi[fi][r] = v.x; nif[fi][r] = v.y;
    }
  float sqj[4], njf[4];
  #pragma unroll
  for (int fj = 0; fj < 4; fj++) {
    float2 v = sqnp[bj * 128 + wc * 64 + fj * 16 + l15];  // C/D col = l15
    sqj[fj] = v.x; njf[fj] = v.y;
  }

  // ---- stage B slab: coalesced 16B/thread x8 -> swizzled ds_write_b128 ----
  {
    const char* gB = fb + (size_t)bj * 128 * 256;
    int tid = threadIdx.x;
    #pragma unroll
    for (int k = 0; k < 4; k++) {
      int f = tid + 512 * k;                          // linear 16B-chunk index 0..2047
      int row = f >> 4, c = f & 15;
      s16x8 v = *reinterpret_cast<const s16x8*>(gB + row * 256 + c * 16);
      int wck = c ^ (row & 7);                        // XOR swizzle on 16B chunk index
      *reinterpret_cast<s16x8*>(smem + row * 256 + wck * 16) = v;
    }
  }
  __syncthreads();

  float sum = 0.0f;

  #pragma unroll
  for (int fj = 0; fj < 4; fj++) {
    int jrow = wc * 64 + fj * 16 + l15;               // local B row (= output col)
    s16x8 B[4];
    #pragma unroll
    for (int ks = 0; ks < 4; ks++) {
      int rc = (ks * 4 + lg) ^ (jrow & 7);
      B[ks] = *reinterpret_cast<const s16x8*>(smem + jrow * 256 + rc * 16);
    }
    long long blab = (lg < 2) ? *reinterpret_cast<const long long*>(
                                    posf8 + (size_t)(bj * 128 + jrow) * KLAB + lg * 8)
                              : 0LL;

    f32x4 acc[2], icc[2];
    #pragma unroll
    for (int fi = 0; fi < 2; fi++) {
      acc[fi] = (f32x4){0.f,0.f,0.f,0.f};
      icc[fi] = (f32x4){0.f,0.f,0.f,0.f};
    }
    #pragma unroll
    for (int ks = 0; ks < 4; ks++)
      #pragma unroll
      for (int fi = 0; fi < 2; fi++)
        acc[fi] = __builtin_amdgcn_mfma_f32_16x16x32_bf16(af[fi][ks], B[ks], acc[fi], 0, 0, 0);
    #pragma unroll
    for (int fi = 0; fi < 2; fi++)                    // inter = pos_i . pos_j on matrix pipe
      icc[fi] = __builtin_amdgcn_mfma_f32_16x16x32_fp8_fp8(alab[fi], blab, icc[fi], 0, 0, 0);

    // hoist per-(fi,r) sums for this fj
    float sqs[2][4], usum[2][4];
    #pragma unroll
    for (int fi = 0; fi < 2; fi++)
      #pragma unroll
      for (int r = 0; r < 4; r++) {
        sqs[fi][r]  = sqi[fi][r] + sqj[fj];
        usum[fi][r] = nif[fi][r] + njf[fj];
      }

    #pragma unroll
    for (int fi = 0; fi < 2; fi++)
      #pragma unroll
      for (int r = 0; r < 4; r++) {
        float inter = icc[fi][r];                     // exact small int as f32
        float d2 = fmaf(-2.0f, acc[fi][r], sqs[fi][r]);
        float t  = FSQRT(FCLAMP(d2));                 // clamp to M^2 folds the min
        float w  = inter * FRCP(usum[fi][r] - inter);
        w = (inter == 0.0f) ? -1.0f : w;
        if (diag) {
          int il = wr * 32 + fi * 16 + lg * 4 + r;
          int jl = wc * 64 + fj * 16 + l15;
          w *= (jl > il) ? 2.0f : ((jl == il) ? 1.0f : 0.0f);
        }
        sum = fmaf(w, t, sum);
      }
  }

  #pragma unroll
  for (int off = 32; off >= 1; off >>= 1) sum += __shfl_xor(sum, off);
  if (lane == 0) bsum[wv] = sum;
  __syncthreads();
  if (threadIdx.x == 0) {
    float s = 0.f;
    #pragma unroll
    for (int w = 0; w < 8; w++) s += bsum[w];
    part[blockIdx.x] = diag ? s : 2.0f * s;   // one plain store per block
  }
}

// Single block: sum 2080 partials (double accum) + apply deferred scales.
__global__ void reduce_kernel(const float* __restrict__ part, float* __restrict__ out) {
  int tid = threadIdx.x;
  double s = 0.0;
  for (int i = tid; i < NTILE; i += 256) s += (double)part[i];
  #pragma unroll
  for (int off = 32; off >= 1; off >>= 1) s += __shfl_xor(s, off);
  __shared__ double wsum[4];
  int wv = tid >> 6, lane = tid & 63;
  if (lane == 0) wsum[wv] = s;
  __syncthreads();
  if (tid == 0) {
    double t = wsum[0] + wsum[1] + wsum[2] + wsum[3];
    // undo deferred scales: /sqrt(128) and /n^2
    out[0] = (float)(t * (1.0 / (11.313708498984760 * 67108864.0)));
  }
}

extern "C" void kernel_launch(void* const* d_in, const int* in_sizes, int n_in,
                              void* d_out, int out_size, void* d_ws, size_t ws_size,
                              hipStream_t stream) {
  const float* feat  = (const float*)d_in[0];
  const int*   label = (const int*)d_in[1];
  char* ws = (char*)d_ws;
  float*          part  = (float*)ws;                            // 2080 floats (16384 B reserved)
  float2*         sqnp  = (float2*)(ws + 16384);                 // 64 KB {sq, npos}
  unsigned char*  posf8 = (unsigned char*)(ws + 16384 + 65536);  // 128 KB fp8 labels
  unsigned short* fbf   = (unsigned short*)(ws + 16384 + 65536 + 131072); // 2 MB bf16 feature
  float* out = (float*)d_out;

  prep_kernel<<<NROW / 16, 256, 0, stream>>>(feat, label, fbf, sqnp, posf8);
  pair_main<<<NTILE, 512, 0, stream>>>(fbf, sqnp, posf8, part);
  reduce_kernel<<<1, 256, 0, stream>>>(part, out);
}

// Round 15
// 55.848 us; speedup vs baseline: 1.2543x; 1.2543x over previous
//
#include <hip/hip_runtime.h>

#define NROW 8192
#define MDIM 128
#define KLAB 16
#define NSLAB 64                     // 8192 / 128 supertile rows
#define NTILE (NSLAB*(NSLAB+1)/2)    // 2080 upper-tri supertiles
#define MARGINP2 288.0f              // (1.5*sqrt(128))^2: clamp bound, min folded into clamp

typedef __attribute__((ext_vector_type(8))) short  s16x8;
typedef __attribute__((ext_vector_type(4))) float  f32x4;

#if __has_builtin(__builtin_amdgcn_sqrtf)
#define FSQRT(x) __builtin_amdgcn_sqrtf(x)
#else
#define FSQRT(x) sqrtf(x)
#endif
#if __has_builtin(__builtin_amdgcn_rcpf)
#define FRCP(x) __builtin_amdgcn_rcpf(x)
#else
#define FRCP(x) (1.0f / (x))
#endif
#if __has_builtin(__builtin_amdgcn_fmed3f)
#define FCLAMP(x) __builtin_amdgcn_fmed3f((x), 0.0f, MARGINP2)
#else
#define FCLAMP(x) fminf(fmaxf((x), 0.0f), MARGINP2)
#endif

__device__ __forceinline__ unsigned short f2bf(float x) {
  unsigned u = __float_as_uint(x);            // RTNE bf16, inputs finite
  return (unsigned short)((u + 0x7FFFu + ((u >> 16) & 1u)) >> 16);
}

// Wave handles 4 rows: bf16 convert + sumsq + npos + fp8 label bytes (1.0 -> 0x38).
__global__ void prep_kernel(const float* __restrict__ feat, const int* __restrict__ label,
                            unsigned short* __restrict__ fbf, float2* __restrict__ sqnp,
                            unsigned char* __restrict__ posf8) {
  int wv = threadIdx.x >> 6, lane = threadIdx.x & 63;
  int sub = lane >> 4, l16 = lane & 15;
  int row = blockIdx.x * 16 + wv * 4 + sub;
  const float* rp = feat + (size_t)row * MDIM + l16 * 8;
  float4 va = *reinterpret_cast<const float4*>(rp);
  float4 vb = *reinterpret_cast<const float4*>(rp + 4);
  s16x8 st;
  st[0]=(short)f2bf(va.x); st[1]=(short)f2bf(va.y); st[2]=(short)f2bf(va.z); st[3]=(short)f2bf(va.w);
  st[4]=(short)f2bf(vb.x); st[5]=(short)f2bf(vb.y); st[6]=(short)f2bf(vb.z); st[7]=(short)f2bf(vb.w);
  *reinterpret_cast<s16x8*>(fbf + (size_t)row * MDIM + l16 * 8) = st;
  float s = va.x*va.x + va.y*va.y + va.z*va.z + va.w*va.w
          + vb.x*vb.x + vb.y*vb.y + vb.z*vb.z + vb.w*vb.w;
  #pragma unroll
  for (int off = 8; off >= 1; off >>= 1) s += __shfl_xor(s, off);   // reduce within 16-lane row group
  int lab = label[((size_t)blockIdx.x * 16 + wv * 4) * KLAB + lane];
  bool on = lab > 0;
  unsigned long long bal = __ballot(on);
  posf8[(size_t)row * KLAB + l16] = on ? 0x38 : 0x00;               // fp8 e4m3 1.0 / 0.0
  if (l16 == 0) {
    unsigned m = (unsigned)((bal >> (sub * 16)) & 0xFFFFull);
    sqnp[row] = make_float2(s, (float)__popc(m));
  }
}

// Block = 8 waves (4x2 grid) = one 128x128 supertile (bi<=bj). R10 staging restored:
// A+B slabs in LDS (64 KB, XOR-swizzled, coalesced) + labels in LDS (4 KB).
// inter = pos_i . pos_j via fp8 MFMA on the idle matrix pipe (verified R14, absmax 0);
// epilogue ~8 instr/elem vs 16 (R13 ablation: epilogue was ~half of pair_main).
__global__ __launch_bounds__(512, 2) void pair_main(
    const unsigned short* __restrict__ fbf, const float2* __restrict__ sqnp,
    const unsigned char* __restrict__ posf8, float* __restrict__ part) {
  __shared__ char smem[69632];            // A [0,32K), B [32K,64K), labA [64K,+2K), labB [66K,+2K)
  __shared__ float bsum[8];

  int bi = 0, rem = blockIdx.x;
  while (rem >= NSLAB - bi) { rem -= NSLAB - bi; bi++; }
  int bj = bi + rem;
  bool diag = (bi == bj);

  int wv = threadIdx.x >> 6, lane = threadIdx.x & 63;
  int l15 = lane & 15, lg = lane >> 4;
  int wr = wv >> 1, wc = wv & 1;          // 4x2 wave grid: 32 rows x 64 cols each
  const char* fb = (const char*)fbf;

  // ---- stage slabs + labels: coalesced 16B/lane -> swizzled ds_write_b128 ----
  {
    const char* gA = fb + (size_t)bi * 128 * 256;
    const char* gB = fb + (size_t)bj * 128 * 256;
    int sub = lane >> 4, c = lane & 15;
    #pragma unroll
    for (int t = 0; t < 4; t++) {
      int lr = wv * 16 + t * 4 + sub;                 // local row 0..127
      s16x8 va = *reinterpret_cast<const s16x8*>(gA + lr * 256 + c * 16);
      s16x8 vb = *reinterpret_cast<const s16x8*>(gB + lr * 256 + c * 16);
      int wck = c ^ (lr & 7);                         // XOR swizzle on 16B chunk index
      *reinterpret_cast<s16x8*>(smem + lr * 256 + wck * 16) = va;
      *reinterpret_cast<s16x8*>(smem + 32768 + lr * 256 + wck * 16) = vb;
    }
    int tid = threadIdx.x;
    if (tid < 256) {                                  // labels: 256 x 16B = 4 KB, linear
      int isB = tid >> 7, row = tid & 127;
      const unsigned char* src = posf8 + ((size_t)((isB ? bj : bi) * 128 + row)) * KLAB;
      s16x8 v = *reinterpret_cast<const s16x8*>(src);
      *reinterpret_cast<s16x8*>(smem + 65536 + isB * 2048 + row * 16) = v;
    }
  }

  // ---- metadata: {sq, npos} packed float2 loads (hoisted, L2-resident) ----
  float sqi[2][4], nif[2][4];
  #pragma unroll
  for (int fi = 0; fi < 2; fi++)
    #pragma unroll
    for (int r = 0; r < 4; r++) {
      float2 v = sqnp[bi * 128 + wr * 32 + fi * 16 + lg * 4 + r];   // C/D row = lg*4 + r
      sqi[fi][r] = v.x; nif[fi][r] = v.y;
    }
  float sqj[4], njf[4];
  #pragma unroll
  for (int fj = 0; fj < 4; fj++) {
    float2 v = sqnp[bj * 128 + wc * 64 + fj * 16 + l15];            // C/D col = l15
    sqj[fj] = v.x; njf[fj] = v.y;
  }

  __syncthreads();

  // ---- A fragments + A labels from LDS ----
  s16x8 af[2][4];
  #pragma unroll
  for (int fi = 0; fi < 2; fi++)
    #pragma unroll
    for (int ks = 0; ks < 4; ks++) {
      int lr = wr * 32 + fi * 16 + l15;
      int rc = (ks * 4 + lg) ^ (lr & 7);
      af[fi][ks] = *reinterpret_cast<const s16x8*>(smem + lr * 256 + rc * 16);
    }
  long long alab[2];
  #pragma unroll
  for (int fi = 0; fi < 2; fi++) {
    int row = wr * 32 + fi * 16 + l15;                // fp8-A fragment row = l15, k-half = lg
    alab[fi] = (lg < 2) ? *reinterpret_cast<const long long*>(smem + 65536 + row * 16 + lg * 8)
                        : 0LL;                        // k=16..31 zero pad
  }

  float sum = 0.0f;

  #pragma unroll
  for (int fj = 0; fj < 4; fj++) {
    int jrow = wc * 64 + fj * 16 + l15;               // local B row (= output col)
    s16x8 B[4];
    #pragma unroll
    for (int ks = 0; ks < 4; ks++) {
      int rc = (ks * 4 + lg) ^ (jrow & 7);
      B[ks] = *reinterpret_cast<const s16x8*>(smem + 32768 + jrow * 256 + rc * 16);
    }
    long long blab = (lg < 2) ? *reinterpret_cast<const long long*>(smem + 67584 + jrow * 16 + lg * 8)
                              : 0LL;

    f32x4 acc[2], icc[2];
    #pragma unroll
    for (int fi = 0; fi < 2; fi++) {
      acc[fi] = (f32x4){0.f,0.f,0.f,0.f};
      icc[fi] = (f32x4){0.f,0.f,0.f,0.f};
    }
    #pragma unroll
    for (int ks = 0; ks < 4; ks++)
      #pragma unroll
      for (int fi = 0; fi < 2; fi++)
        acc[fi] = __builtin_amdgcn_mfma_f32_16x16x32_bf16(af[fi][ks], B[ks], acc[fi], 0, 0, 0);
    #pragma unroll
    for (int fi = 0; fi < 2; fi++)                    // inter = pos_i . pos_j on matrix pipe
      icc[fi] = __builtin_amdgcn_mfma_f32_16x16x32_fp8_fp8(alab[fi], blab, icc[fi], 0, 0, 0);

    float sqs[2][4], usum[2][4];
    #pragma unroll
    for (int fi = 0; fi < 2; fi++)
      #pragma unroll
      for (int r = 0; r < 4; r++) {
        sqs[fi][r]  = sqi[fi][r] + sqj[fj];
        usum[fi][r] = nif[fi][r] + njf[fj];
      }

    #pragma unroll
    for (int fi = 0; fi < 2; fi++)
      #pragma unroll
      for (int r = 0; r < 4; r++) {
        float inter = icc[fi][r];                     // exact small int as f32
        float d2 = fmaf(-2.0f, acc[fi][r], sqs[fi][r]);
        float t  = FSQRT(FCLAMP(d2));                 // clamp to M^2 folds the min
        float w  = inter * FRCP(usum[fi][r] - inter);
        w = (inter == 0.0f) ? -1.0f : w;
        if (diag) {
          int il = wr * 32 + fi * 16 + lg * 4 + r;
          int jl = wc * 64 + fj * 16 + l15;
          w *= (jl > il) ? 2.0f : ((jl == il) ? 1.0f : 0.0f);
        }
        sum = fmaf(w, t, sum);
      }
  }

  #pragma unroll
  for (int off = 32; off >= 1; off >>= 1) sum += __shfl_xor(sum, off);
  if (lane == 0) bsum[wv] = sum;
  __syncthreads();
  if (threadIdx.x == 0) {
    float s = 0.f;
    #pragma unroll
    for (int w = 0; w < 8; w++) s += bsum[w];
    part[blockIdx.x] = diag ? s : 2.0f * s;   // one plain store per block
  }
}

// Single block: sum 2080 partials (double accum) + apply deferred scales.
__global__ void reduce_kernel(const float* __restrict__ part, float* __restrict__ out) {
  int tid = threadIdx.x;
  double s = 0.0;
  for (int i = tid; i < NTILE; i += 256) s += (double)part[i];
  #pragma unroll
  for (int off = 32; off >= 1; off >>= 1) s += __shfl_xor(s, off);
  __shared__ double wsum[4];
  int wv = tid >> 6, lane = tid & 63;
  if (lane == 0) wsum[wv] = s;
  __syncthreads();
  if (tid == 0) {
    double t = wsum[0] + wsum[1] + wsum[2] + wsum[3];
    // undo deferred scales: /sqrt(128) and /n^2
    out[0] = (float)(t * (1.0 / (11.313708498984760 * 67108864.0)));
  }
}

extern "C" void kernel_launch(void* const* d_in, const int* in_sizes, int n_in,
                              void* d_out, int out_size, void* d_ws, size_t ws_size,
                              hipStream_t stream) {
  const float* feat  = (const float*)d_in[0];
  const int*   label = (const int*)d_in[1];
  char* ws = (char*)d_ws;
  float*          part  = (float*)ws;                            // 2080 floats (16384 B reserved)
  float2*         sqnp  = (float2*)(ws + 16384);                 // 64 KB {sq, npos}
  unsigned char*  posf8 = (unsigned char*)(ws + 16384 + 65536);  // 128 KB fp8 labels
  unsigned short* fbf   = (unsigned short*)(ws + 16384 + 65536 + 131072); // 2 MB bf16 feature
  float* out = (float*)d_out;

  prep_kernel<<<NROW / 16, 256, 0, stream>>>(feat, label, fbf, sqnp, posf8);
  pair_main<<<NTILE, 512, 0, stream>>>(fbf, sqnp, posf8, part);
  reduce_kernel<<<1, 256, 0, stream>>>(part, out);
}

// Round 16
// 46.027 us; speedup vs baseline: 1.5219x; 1.2134x over previous
//
#include <hip/hip_runtime.h>

#define NROW 8192
#define MDIM 128
#define KLAB 16
#define NSLAB 64                     // 8192 / 128 supertile rows
#define NTILE (NSLAB*(NSLAB+1)/2)    // 2080 upper-tri supertiles
#define MARGINP2 288.0f              // (1.5*sqrt(128))^2: clamp bound, min folded into clamp

typedef __attribute__((ext_vector_type(8))) short  s16x8;
typedef __attribute__((ext_vector_type(4))) float  f32x4;

#if __has_builtin(__builtin_amdgcn_sqrtf)
#define FSQRT(x) __builtin_amdgcn_sqrtf(x)
#else
#define FSQRT(x) sqrtf(x)
#endif
#if __has_builtin(__builtin_amdgcn_rcpf)
#define FRCP(x) __builtin_amdgcn_rcpf(x)
#else
#define FRCP(x) (1.0f / (x))
#endif
#if __has_builtin(__builtin_amdgcn_fmed3f)
#define FCLAMP(x) __builtin_amdgcn_fmed3f((x), 0.0f, MARGINP2)
#else
#define FCLAMP(x) fminf(fmaxf((x), 0.0f), MARGINP2)
#endif

__device__ __forceinline__ unsigned short f2bf(float x) {
  unsigned u = __float_as_uint(x);            // RTNE bf16, inputs finite
  return (unsigned short)((u + 0x7FFFu + ((u >> 16) & 1u)) >> 16);
}

// Wave handles 4 rows (16 lanes/row, 8 floats/lane): bf16 convert + sumsq + label mask.
__global__ void prep_kernel(const float* __restrict__ feat, const int* __restrict__ label,
                            unsigned short* __restrict__ fbf, float* __restrict__ sq,
                            int* __restrict__ maskA) {
  int wv = threadIdx.x >> 6, lane = threadIdx.x & 63;
  int sub = lane >> 4, l16 = lane & 15;
  int row = blockIdx.x * 16 + wv * 4 + sub;
  const float* rp = feat + (size_t)row * MDIM + l16 * 8;
  float4 va = *reinterpret_cast<const float4*>(rp);
  float4 vb = *reinterpret_cast<const float4*>(rp + 4);
  s16x8 st;
  st[0]=(short)f2bf(va.x); st[1]=(short)f2bf(va.y); st[2]=(short)f2bf(va.z); st[3]=(short)f2bf(va.w);
  st[4]=(short)f2bf(vb.x); st[5]=(short)f2bf(vb.y); st[6]=(short)f2bf(vb.z); st[7]=(short)f2bf(vb.w);
  *reinterpret_cast<s16x8*>(fbf + (size_t)row * MDIM + l16 * 8) = st;
  float s = va.x*va.x + va.y*va.y + va.z*va.z + va.w*va.w
          + vb.x*vb.x + vb.y*vb.y + vb.z*vb.z + vb.w*vb.w;
  #pragma unroll
  for (int off = 8; off >= 1; off >>= 1) s += __shfl_xor(s, off);   // reduce within 16-lane row group
  int lab = label[((size_t)blockIdx.x * 16 + wv * 4) * KLAB + lane];
  unsigned long long bal = __ballot(lab > 0);
  if (l16 == 0) {
    sq[row]    = s;
    maskA[row] = (int)(unsigned)((bal >> (sub * 16)) & 0xFFFFull);
  }
}

// Block = 8 waves (4x2 grid) = one 128x128 supertile (bi<=bj). R10 inner loop EXACTLY
// (best known: 40.1 us total). Changed vs R10: B-only LDS (32 KB) + A fragments loaded
// once from L2-resident global pre-barrier + __launch_bounds__(512,3) -> 3 blocks/CU
// = 24 waves/CU (the untested occupancy x staging cell; 64KB LDS pinned all prior
// variants at 2 blocks/CU with ~60% stall).
// mfma_f32_16x16x32_bf16 layout as verified in round 2 (absmax == 0).
__global__ __launch_bounds__(512, 3) void pair_main(
    const unsigned short* __restrict__ fbf, const float* __restrict__ sq,
    const int* __restrict__ maskA, float* __restrict__ part) {
  __shared__ char smem[32768];            // B slab only
  __shared__ float bsum[8];

  int bi = 0, rem = blockIdx.x;
  while (rem >= NSLAB - bi) { rem -= NSLAB - bi; bi++; }
  int bj = bi + rem;
  bool diag = (bi == bj);

  int wv = threadIdx.x >> 6, lane = threadIdx.x & 63;
  int l15 = lane & 15, lg = lane >> 4;
  int wr = wv >> 1, wc = wv & 1;          // 4x2 wave grid: 32 rows x 64 cols each
  const char* fb = (const char*)fbf;
  int arow = bi * 128 + wr * 32;

  // ---- A fragments once from global (L2-resident 2MB), issued before B staging ----
  s16x8 af[2][4];
  #pragma unroll
  for (int fi = 0; fi < 2; fi++)
    #pragma unroll
    for (int ks = 0; ks < 4; ks++)
      af[fi][ks] = *reinterpret_cast<const s16x8*>(
          fb + (size_t)(arow + fi * 16 + l15) * 256 + ks * 64 + lg * 16);

  // ---- metadata (hoisted; from L2-resident 32KB arrays) ----
  float sqi[2][4]; int mi[2][4];
  #pragma unroll
  for (int fi = 0; fi < 2; fi++)
    #pragma unroll
    for (int r = 0; r < 4; r++) {
      int ir = arow + fi * 16 + lg * 4 + r;                 // C/D row = lg*4 + r
      sqi[fi][r] = sq[ir]; mi[fi][r] = maskA[ir];
    }
  float sqj[4]; int mj[4];
  #pragma unroll
  for (int fj = 0; fj < 4; fj++) {
    int jr = bj * 128 + wc * 64 + fj * 16 + l15;            // C/D col = l15
    sqj[fj] = sq[jr]; mj[fj] = maskA[jr];
  }

  // ---- stage B slab: coalesced 16B/thread x4 -> swizzled ds_write_b128 ----
  {
    const char* gB = fb + (size_t)bj * 128 * 256;
    int tid = threadIdx.x;
    #pragma unroll
    for (int k = 0; k < 4; k++) {
      int f = tid + 512 * k;                          // linear 16B-chunk index 0..2047
      int row = f >> 4, c = f & 15;
      s16x8 v = *reinterpret_cast<const s16x8*>(gB + row * 256 + c * 16);
      int wck = c ^ (row & 7);                        // XOR swizzle on 16B chunk index
      *reinterpret_cast<s16x8*>(smem + row * 256 + wck * 16) = v;
    }
  }
  __syncthreads();

  float sum = 0.0f;

  #pragma unroll
  for (int fj = 0; fj < 4; fj++) {
    s16x8 B[4];
    #pragma unroll
    for (int ks = 0; ks < 4; ks++) {
      int lr = wc * 64 + fj * 16 + l15;
      int rc = (ks * 4 + lg) ^ (lr & 7);
      B[ks] = *reinterpret_cast<const s16x8*>(smem + lr * 256 + rc * 16);
    }

    f32x4 acc[2];
    acc[0] = (f32x4){0.f,0.f,0.f,0.f}; acc[1] = (f32x4){0.f,0.f,0.f,0.f};
    #pragma unroll
    for (int ks = 0; ks < 4; ks++)
      #pragma unroll
      for (int fi = 0; fi < 2; fi++)
        acc[fi] = __builtin_amdgcn_mfma_f32_16x16x32_bf16(af[fi][ks], B[ks], acc[fi], 0, 0, 0);

    #pragma unroll
    for (int fi = 0; fi < 2; fi++)
      #pragma unroll
      for (int r = 0; r < 4; r++) {
        float g  = acc[fi][r];
        float d2 = fmaf(-2.0f, g, sqi[fi][r] + sqj[fj]);
        float t  = FSQRT(FCLAMP(d2));
        int inter = __popc(mi[fi][r] & mj[fj]);
        int uni   = __popc(mi[fi][r] | mj[fj]);
        float w = (float)inter * FRCP((float)uni);
        w = (inter == 0) ? -1.0f : w;
        if (diag) {
          int il = wr * 32 + fi * 16 + lg * 4 + r;
          int jl = wc * 64 + fj * 16 + l15;
          w *= (jl > il) ? 2.0f : ((jl == il) ? 1.0f : 0.0f);
        }
        sum = fmaf(w, t, sum);
      }
  }

  #pragma unroll
  for (int off = 32; off >= 1; off >>= 1) sum += __shfl_xor(sum, off);
  if (lane == 0) bsum[wv] = sum;
  __syncthreads();
  if (threadIdx.x == 0) {
    float s = 0.f;
    #pragma unroll
    for (int w = 0; w < 8; w++) s += bsum[w];
    part[blockIdx.x] = diag ? s : 2.0f * s;   // one plain store per block
  }
}

// Single block: sum 2080 partials (double accum) + apply deferred scales.
__global__ void reduce_kernel(const float* __restrict__ part, float* __restrict__ out) {
  int tid = threadIdx.x;
  double s = 0.0;
  for (int i = tid; i < NTILE; i += 256) s += (double)part[i];
  #pragma unroll
  for (int off = 32; off >= 1; off >>= 1) s += __shfl_xor(s, off);
  __shared__ double wsum[4];
  int wv = tid >> 6, lane = tid & 63;
  if (lane == 0) wsum[wv] = s;
  __syncthreads();
  if (tid == 0) {
    double t = wsum[0] + wsum[1] + wsum[2] + wsum[3];
    // undo deferred scales: /sqrt(128) and /n^2
    out[0] = (float)(t * (1.0 / (11.313708498984760 * 67108864.0)));
  }
}

extern "C" void kernel_launch(void* const* d_in, const int* in_sizes, int n_in,
                              void* d_out, int out_size, void* d_ws, size_t ws_size,
                              hipStream_t stream) {
  const float* feat  = (const float*)d_in[0];
  const int*   label = (const int*)d_in[1];
  char* ws = (char*)d_ws;
  float* part           = (float*)ws;                           // 2080 floats (8448 B reserved)
  float* sq             = (float*)(ws + 8448);                  // 32 KB
  int*   maskA          = (int*)(ws + 8448 + 32768);            // 32 KB
  unsigned short* fbf   = (unsigned short*)(ws + 8448 + 65536); // 2 MB bf16 feature
  float* out = (float*)d_out;

  prep_kernel<<<NROW / 16, 256, 0, stream>>>(feat, label, fbf, sq, maskA);
  pair_main<<<NTILE, 512, 0, stream>>>(fbf, sq, maskA, part);
  reduce_kernel<<<1, 256, 0, stream>>>(part, out);
}